// Round 1
// baseline (87.771 us; speedup 1.0000x reference)
//
#include <hip/hip_runtime.h>
#include <math.h>

#define B_   32
#define N_   512
#define W_   256
#define BN_  (B_*N_)        // 16384
#define NBLK_A 4096         // BN_/4 rows-per-block

__device__ __forceinline__ float wave_reduce_sum64(float v) {
#pragma unroll
    for (int m = 32; m >= 1; m >>= 1) v += __shfl_xor(v, m);
    return v;
}

// ---------------------------------------------------------------------------
// Kernel A: per (b,n) row — MSTCN(mean-trick) -> z -> recon, act stats, GAT h/e
// one wave per row, 4 rows per 256-thread block
// ---------------------------------------------------------------------------
__global__ __launch_bounds__(256) void kA(
    const float* __restrict__ x,
    const float* __restrict__ w2, const float* __restrict__ b2,
    const float* __restrict__ w3, const float* __restrict__ b3,
    const float* __restrict__ w5, const float* __restrict__ b5,
    const float* __restrict__ w7, const float* __restrict__ b7,
    const float* __restrict__ enc_w, const float* __restrict__ enc_b,
    const float* __restrict__ dec_w, const float* __restrict__ dec_b,
    const float* __restrict__ se,
    const float* __restrict__ g0w, const float* __restrict__ g0s, const float* __restrict__ g0d,
    const float* __restrict__ g1w, const float* __restrict__ g1s, const float* __restrict__ g1d,
    float* __restrict__ out_recon, float* __restrict__ out_sdev,
    float* __restrict__ ws_h, float* __restrict__ ws_e, float* __restrict__ ws_rho)
{
    __shared__ float lds_rho[4][8];
    const int wave = threadIdx.x >> 6;
    const int lane = threadIdx.x & 63;
    const int r = (blockIdx.x << 2) + wave;      // row id in [0, BN_)
    const int n = r & (N_ - 1);

    // ---- load row of x: 64 lanes x float4 = 256 floats
    const float4 xv = reinterpret_cast<const float4*>(x)[r * 64 + lane];
    const float S = wave_reduce_sum64(xv.x + xv.y + xv.z + xv.w);
    const float P1 = __shfl(xv.x, 0);
    const float P2 = P1 + __shfl(xv.y, 0);
    const float P3 = P2 + __shfl(xv.z, 0);
    const float Q1 = __shfl(xv.w, 63);
    const float Q2 = Q1 + __shfl(xv.z, 63);
    const float Q3 = Q2 + __shfl(xv.y, 63);

    // ---- node_feat: one channel per lane. feats order: k=2,3,5,7 x 16ch
    const int ki = lane >> 4, c = lane & 15;
    const int k  = (ki == 0) ? 2 : (ki == 1) ? 3 : (ki == 2) ? 5 : 7;
    const int pl = (k - 1) >> 1;
    const float* cw = (ki == 0) ? w2 : (ki == 1) ? w3 : (ki == 2) ? w5 : w7;
    const float* cb = (ki == 0) ? b2 : (ki == 1) ? b3 : (ki == 2) ? b5 : b7;
    float acc = 0.f;
    for (int j = 0; j < k; ++j) {
        const int o = j - pl;
        const float corr = (o == 0) ? 0.f :
                           (o == 1) ? P1 : (o == 2) ? P2 : (o == 3) ? P3 :
                           (o == -1) ? Q1 : (o == -2) ? Q2 : Q3;
        acc += cw[c * k + j] * (S - corr);
    }
    const float nf = cb[c] + acc * (1.0f / (float)W_);

    // ---- z[8] = node_feat @ enc_w + enc_b   (reduce across 64 lanes)
    float z[8];
    {
        const float4 e0 = reinterpret_cast<const float4*>(enc_w)[lane * 2];
        const float4 e1 = reinterpret_cast<const float4*>(enc_w)[lane * 2 + 1];
        z[0] = nf * e0.x; z[1] = nf * e0.y; z[2] = nf * e0.z; z[3] = nf * e0.w;
        z[4] = nf * e1.x; z[5] = nf * e1.y; z[6] = nf * e1.z; z[7] = nf * e1.w;
#pragma unroll
        for (int zi = 0; zi < 8; ++zi) z[zi] = wave_reduce_sum64(z[zi]) + enc_b[zi];
    }

    // ---- recon row = z @ dec_w + dec_b  (4 outputs per lane, float4 store)
    {
        float4 rec = reinterpret_cast<const float4*>(dec_b)[lane];
#pragma unroll
        for (int zi = 0; zi < 8; ++zi) {
            const float4 dw = reinterpret_cast<const float4*>(dec_w)[zi * 64 + lane];
            rec.x += z[zi] * dw.x; rec.y += z[zi] * dw.y;
            rec.z += z[zi] * dw.z; rec.w += z[zi] * dw.w;
        }
        reinterpret_cast<float4*>(out_recon)[r * 64 + lane] = rec;
    }

    // ---- act stats: sparsity_dev + rho partial sums
    float act[8]; float sd = 0.f;
#pragma unroll
    for (int zi = 0; zi < 8; ++zi) {
        act[zi] = 1.0f / (1.0f + expf(-z[zi]));
        sd += fabsf(act[zi] - 0.05f);
    }
    if (lane == 0) {
        out_sdev[r] = sd * 0.125f;
#pragma unroll
        for (int zi = 0; zi < 8; ++zi) lds_rho[wave][zi] = act[zi];
    }
    __syncthreads();
    if (threadIdx.x < 8) {
        const float t = lds_rho[0][threadIdx.x] + lds_rho[1][threadIdx.x]
                      + lds_rho[2][threadIdx.x] + lds_rho[3][threadIdx.x];
        ws_rho[(blockIdx.x << 3) + threadIdx.x] = t;
    }

    // ---- GAT precompute: h0/h1 (16 each), e_src/e_dst per head
    if (lane < 32) {
        const int d = lane & 15;
        const int head = lane >> 4;
        const float* gw = head ? g1w : g0w;
        float hv = 0.f;
#pragma unroll
        for (int f = 0; f < 8; ++f) hv += z[f] * gw[f * 16 + d];
#pragma unroll
        for (int f = 0; f < 8; ++f) hv += se[n * 8 + f] * gw[(8 + f) * 16 + d];
        ws_h[(size_t)r * 32 + lane] = hv;   // [0..15]=h0, [16..31]=h1
        const float* as = head ? g1s : g0s;
        const float* ad = head ? g1d : g0d;
        float ps = hv * as[d];
        float pd = hv * ad[d];
#pragma unroll
        for (int m = 8; m >= 1; m >>= 1) {
            ps += __shfl_xor(ps, m);
            pd += __shfl_xor(pd, m);
        }
        if (d == 0) {
            ws_e[(size_t)r * 4 + head * 2 + 0] = ps;  // e_src
            ws_e[(size_t)r * 4 + head * 2 + 1] = pd;  // e_dst
        }
    }
}

// ---------------------------------------------------------------------------
// Kernel C0: normalize sensor_emb rows
// ---------------------------------------------------------------------------
__global__ __launch_bounds__(256) void kC0(const float* __restrict__ se,
                                           float* __restrict__ en)
{
    const int i = blockIdx.x * 256 + threadIdx.x;
    if (i >= N_) return;
    float v[8]; float ss = 0.f;
#pragma unroll
    for (int e = 0; e < 8; ++e) { v[e] = se[i * 8 + e]; ss += v[e] * v[e]; }
    const float inv = 1.0f / fmaxf(sqrtf(ss), 1e-12f);
#pragma unroll
    for (int e = 0; e < 8; ++e) en[i * 8 + e] = v[e] * inv;
}

// ---------------------------------------------------------------------------
// Kernel C1: per-row top-20 neighbor selection (one wave per row)
// adjacency[i] = {i} ∪ { j in top20(sim row, diag=-inf) : sim>0 }
// ---------------------------------------------------------------------------
__global__ __launch_bounds__(256) void kC1(const float* __restrict__ en,
                                           int* __restrict__ adj)
{
    const int wave = threadIdx.x >> 6;
    const int lane = threadIdx.x & 63;
    const int i = (blockIdx.x << 2) + wave;
    float ei[8];
#pragma unroll
    for (int e = 0; e < 8; ++e) ei[e] = en[i * 8 + e];
    float v[8];
#pragma unroll
    for (int q = 0; q < 8; ++q) {
        const int j = (q << 6) + lane;
        float d = 0.f;
#pragma unroll
        for (int e = 0; e < 8; ++e) d += ei[e] * en[j * 8 + e];
        v[q] = (j == i) ? -3.4e38f : d * 0.35355339059327373f;  // 1/sqrt(8)
    }
    int cnt = 1;
    if (lane == 0) adj[i * 24 + 1] = i;          // self first
    for (int it = 0; it < 20; ++it) {
        float bv = v[0]; int bq = 0;
#pragma unroll
        for (int q = 1; q < 8; ++q) if (v[q] > bv) { bv = v[q]; bq = q; }
        int bj = (bq << 6) + lane;
#pragma unroll
        for (int m = 32; m >= 1; m >>= 1) {
            const float ov = __shfl_xor(bv, m);
            const int   oj = __shfl_xor(bj, m);
            if (ov > bv || (ov == bv && oj < bj)) { bv = ov; bj = oj; }
        }
        if (bv <= 0.f) break;                     // relu would mask the rest
        if (lane == 0) adj[i * 24 + 1 + cnt] = bj;
        cnt++;
        const int wq = bj >> 6, wl = bj & 63;
#pragma unroll
        for (int q = 0; q < 8; ++q) if (q == wq && lane == wl) v[q] = -3.4e38f;
    }
    if (lane == 0) adj[i * 24] = cnt;
}

// ---------------------------------------------------------------------------
// Kernel B: reduce rho partials -> KL scalar
// ---------------------------------------------------------------------------
__global__ __launch_bounds__(64) void kB(const float* __restrict__ ws_rho,
                                         float* __restrict__ out_kl)
{
    const int lane = threadIdx.x;
    float t[8] = {0, 0, 0, 0, 0, 0, 0, 0};
    for (int i = lane; i < NBLK_A; i += 64) {
        const float4 a = reinterpret_cast<const float4*>(ws_rho)[i * 2];
        const float4 b = reinterpret_cast<const float4*>(ws_rho)[i * 2 + 1];
        t[0] += a.x; t[1] += a.y; t[2] += a.z; t[3] += a.w;
        t[4] += b.x; t[5] += b.y; t[6] += b.z; t[7] += b.w;
    }
#pragma unroll
    for (int zi = 0; zi < 8; ++zi) t[zi] = wave_reduce_sum64(t[zi]);
    if (lane == 0) {
        float kl = 0.f;
#pragma unroll
        for (int zi = 0; zi < 8; ++zi) {
            float rh = t[zi] * (1.0f / (float)BN_);
            rh = fminf(fmaxf(rh, 1e-6f), 1.0f - 1e-6f);
            kl += 0.05f * logf(0.05f / rh) + 0.95f * logf(0.95f / (1.0f - rh));
        }
        out_kl[0] = kl;
    }
}

// ---------------------------------------------------------------------------
// Kernel D: sparse GAT aggregation + proj(ELU) + head
// half-wave (32 lanes) per (b,i) row; 8 rows per 256-thread block
// ---------------------------------------------------------------------------
__global__ __launch_bounds__(256) void kD(
    const float* __restrict__ ws_h, const float* __restrict__ ws_e,
    const int* __restrict__ adj,
    const float* __restrict__ proj_w, const float* __restrict__ proj_b,
    const float* __restrict__ head_w, const float* __restrict__ head_b,
    float* __restrict__ out_pred)
{
    __shared__ float lds[8][32];
    const int lane = threadIdx.x & 63;
    const int wave = threadIdx.x >> 6;
    const int half = lane >> 5;
    const int d = lane & 31;                  // output channel (h0:0-15, h1:16-31)
    const int ri = (wave << 1) + half;
    const int r = (blockIdx.x << 3) + ri;     // (b,i) row
    const int b = r >> 9;
    const int i = r & (N_ - 1);
    const int head = d >> 4;
    const int cnt = adj[i * 24];
    const float esrc = ws_e[(size_t)r * 4 + (head << 1)];

    // pass 1: max over neighbors
    float m = -3.4e38f;
    for (int t = 0; t < cnt; ++t) {
        const int j = adj[i * 24 + 1 + t];
        const float ed = ws_e[(size_t)((b << 9) | j) * 4 + (head << 1) + 1];
        float e = esrc + ed;
        e = (e >= 0.f) ? e : 0.2f * e;
        m = fmaxf(m, e);
    }
    // pass 2: softmax-weighted aggregation of h
    float s = 0.f, accv = 0.f;
    for (int t = 0; t < cnt; ++t) {
        const int j = adj[i * 24 + 1 + t];
        const int rj = (b << 9) | j;
        const float ed = ws_e[(size_t)rj * 4 + (head << 1) + 1];
        float e = esrc + ed;
        e = (e >= 0.f) ? e : 0.2f * e;
        const float w = expf(e - m);
        s += w;
        accv += w * ws_h[(size_t)rj * 32 + d];
    }
    lds[ri][d] = accv / s;
    __syncthreads();

    // proj + ELU + head
    float f = proj_b[d];
#pragma unroll
    for (int dd = 0; dd < 32; ++dd) f += lds[ri][dd] * proj_w[dd * 32 + d];
    f = (f > 0.f) ? f : expm1f(f);
    float p = f * head_w[d];
#pragma unroll
    for (int mm = 16; mm >= 1; mm >>= 1) p += __shfl_xor(p, mm);
    if (d == 0) out_pred[r] = p + head_b[0];
}

// ---------------------------------------------------------------------------
extern "C" void kernel_launch(void* const* d_in, const int* in_sizes, int n_in,
                              void* d_out, int out_size, void* d_ws, size_t ws_size,
                              hipStream_t stream)
{
    (void)in_sizes; (void)n_in; (void)out_size; (void)ws_size;
    const float* x     = (const float*)d_in[0];
    const float* w2    = (const float*)d_in[1];
    const float* b2    = (const float*)d_in[2];
    const float* w3    = (const float*)d_in[3];
    const float* b3    = (const float*)d_in[4];
    const float* w5    = (const float*)d_in[5];
    const float* b5    = (const float*)d_in[6];
    const float* w7    = (const float*)d_in[7];
    const float* b7    = (const float*)d_in[8];
    const float* enc_w = (const float*)d_in[9];
    const float* enc_b = (const float*)d_in[10];
    const float* dec_w = (const float*)d_in[11];
    const float* dec_b = (const float*)d_in[12];
    const float* se    = (const float*)d_in[13];
    const float* g0w   = (const float*)d_in[14];
    const float* g0s   = (const float*)d_in[15];
    const float* g0d   = (const float*)d_in[16];
    const float* g1w   = (const float*)d_in[17];
    const float* g1s   = (const float*)d_in[18];
    const float* g1d   = (const float*)d_in[19];
    const float* pw    = (const float*)d_in[20];
    const float* pb    = (const float*)d_in[21];
    const float* hw    = (const float*)d_in[22];
    const float* hb    = (const float*)d_in[23];

    float* out       = (float*)d_out;
    float* out_pred  = out;                          // 16384
    float* out_recon = out + 16384;                  // 4194304
    float* out_kl    = out + 16384 + 4194304;        // 1
    float* out_sdev  = out_kl + 1;                   // 16384

    float* ws_h   = (float*)d_ws;                    // BN_*32
    float* ws_e   = ws_h + (size_t)BN_ * 32;         // BN_*4
    float* ws_rho = ws_e + (size_t)BN_ * 4;          // NBLK_A*8
    float* ws_en  = ws_rho + (size_t)NBLK_A * 8;     // N_*8
    int*   ws_adj = (int*)(ws_en + (size_t)N_ * 8);  // N_*24 ints

    hipLaunchKernelGGL(kA, dim3(NBLK_A), dim3(256), 0, stream,
                       x, w2, b2, w3, b3, w5, b5, w7, b7,
                       enc_w, enc_b, dec_w, dec_b, se,
                       g0w, g0s, g0d, g1w, g1s, g1d,
                       out_recon, out_sdev, ws_h, ws_e, ws_rho);
    hipLaunchKernelGGL(kC0, dim3(2), dim3(256), 0, stream, se, ws_en);
    hipLaunchKernelGGL(kC1, dim3(N_ / 4), dim3(256), 0, stream, ws_en, ws_adj);
    hipLaunchKernelGGL(kB, dim3(1), dim3(64), 0, stream, ws_rho, out_kl);
    hipLaunchKernelGGL(kD, dim3(BN_ / 8), dim3(256), 0, stream,
                       ws_h, ws_e, ws_adj, pw, pb, hw, hb, out_pred);
}

// Round 3
// 66.736 us; speedup vs baseline: 1.3152x; 1.3152x over previous
//
#include <hip/hip_runtime.h>
#include <math.h>

#define B_   32
#define N_   512
#define W_   256
#define BN_  (B_*N_)        // 16384
#define NBLK_A 4096         // BN_/4 rows-per-block

__device__ __forceinline__ float wave_reduce_sum64(float v) {
#pragma unroll
    for (int m = 32; m >= 1; m >>= 1) v += __shfl_xor(v, m);
    return v;
}

// ---------------------------------------------------------------------------
// Kernel A: per (b,n) row — MSTCN(mean-trick) -> z -> recon, act stats, GAT h/e
// one wave per row, 4 rows per 256-thread block
// ---------------------------------------------------------------------------
__global__ __launch_bounds__(256) void kA(
    const float* __restrict__ x,
    const float* __restrict__ w2, const float* __restrict__ b2,
    const float* __restrict__ w3, const float* __restrict__ b3,
    const float* __restrict__ w5, const float* __restrict__ b5,
    const float* __restrict__ w7, const float* __restrict__ b7,
    const float* __restrict__ enc_w, const float* __restrict__ enc_b,
    const float* __restrict__ dec_w, const float* __restrict__ dec_b,
    const float* __restrict__ se,
    const float* __restrict__ g0w, const float* __restrict__ g0s, const float* __restrict__ g0d,
    const float* __restrict__ g1w, const float* __restrict__ g1s, const float* __restrict__ g1d,
    float* __restrict__ out_recon, float* __restrict__ out_sdev,
    float* __restrict__ ws_h, float* __restrict__ ws_e, float* __restrict__ ws_rho)
{
    __shared__ float lds_rho[4][8];
    const int wave = threadIdx.x >> 6;
    const int lane = threadIdx.x & 63;
    const int r = (blockIdx.x << 2) + wave;      // row id in [0, BN_)
    const int n = r & (N_ - 1);

    // ---- load row of x: 64 lanes x float4 = 256 floats
    const float4 xv = reinterpret_cast<const float4*>(x)[r * 64 + lane];
    const float S = wave_reduce_sum64(xv.x + xv.y + xv.z + xv.w);
    const float P1 = __shfl(xv.x, 0);
    const float P2 = P1 + __shfl(xv.y, 0);
    const float P3 = P2 + __shfl(xv.z, 0);
    const float Q1 = __shfl(xv.w, 63);
    const float Q2 = Q1 + __shfl(xv.z, 63);
    const float Q3 = Q2 + __shfl(xv.y, 63);

    // ---- node_feat: one channel per lane. feats order: k=2,3,5,7 x 16ch
    const int ki = lane >> 4, c = lane & 15;
    const int k  = (ki == 0) ? 2 : (ki == 1) ? 3 : (ki == 2) ? 5 : 7;
    const int pl = (k - 1) >> 1;
    const float* cw = (ki == 0) ? w2 : (ki == 1) ? w3 : (ki == 2) ? w5 : w7;
    const float* cb = (ki == 0) ? b2 : (ki == 1) ? b3 : (ki == 2) ? b5 : b7;
    float acc = 0.f;
    for (int j = 0; j < k; ++j) {
        const int o = j - pl;
        const float corr = (o == 0) ? 0.f :
                           (o == 1) ? P1 : (o == 2) ? P2 : (o == 3) ? P3 :
                           (o == -1) ? Q1 : (o == -2) ? Q2 : Q3;
        acc += cw[c * k + j] * (S - corr);
    }
    const float nf = cb[c] + acc * (1.0f / (float)W_);

    // ---- z[8] = node_feat @ enc_w + enc_b   (reduce across 64 lanes)
    float z[8];
    {
        const float4 e0 = reinterpret_cast<const float4*>(enc_w)[lane * 2];
        const float4 e1 = reinterpret_cast<const float4*>(enc_w)[lane * 2 + 1];
        z[0] = nf * e0.x; z[1] = nf * e0.y; z[2] = nf * e0.z; z[3] = nf * e0.w;
        z[4] = nf * e1.x; z[5] = nf * e1.y; z[6] = nf * e1.z; z[7] = nf * e1.w;
#pragma unroll
        for (int zi = 0; zi < 8; ++zi) z[zi] = wave_reduce_sum64(z[zi]) + enc_b[zi];
    }

    // ---- recon row = z @ dec_w + dec_b  (4 outputs per lane, float4 store)
    {
        float4 rec = reinterpret_cast<const float4*>(dec_b)[lane];
#pragma unroll
        for (int zi = 0; zi < 8; ++zi) {
            const float4 dw = reinterpret_cast<const float4*>(dec_w)[zi * 64 + lane];
            rec.x += z[zi] * dw.x; rec.y += z[zi] * dw.y;
            rec.z += z[zi] * dw.z; rec.w += z[zi] * dw.w;
        }
        reinterpret_cast<float4*>(out_recon)[r * 64 + lane] = rec;
    }

    // ---- act stats: sparsity_dev + rho partial sums
    float act[8]; float sd = 0.f;
#pragma unroll
    for (int zi = 0; zi < 8; ++zi) {
        act[zi] = 1.0f / (1.0f + expf(-z[zi]));
        sd += fabsf(act[zi] - 0.05f);
    }
    if (lane == 0) {
        out_sdev[r] = sd * 0.125f;
#pragma unroll
        for (int zi = 0; zi < 8; ++zi) lds_rho[wave][zi] = act[zi];
    }
    __syncthreads();
    if (threadIdx.x < 8) {
        const float t = lds_rho[0][threadIdx.x] + lds_rho[1][threadIdx.x]
                      + lds_rho[2][threadIdx.x] + lds_rho[3][threadIdx.x];
        ws_rho[(blockIdx.x << 3) + threadIdx.x] = t;
    }

    // ---- GAT precompute: h0/h1 (16 each), e_src/e_dst per head
    if (lane < 32) {
        const int d = lane & 15;
        const int head = lane >> 4;
        const float* gw = head ? g1w : g0w;
        float hv = 0.f;
#pragma unroll
        for (int f = 0; f < 8; ++f) hv += z[f] * gw[f * 16 + d];
#pragma unroll
        for (int f = 0; f < 8; ++f) hv += se[n * 8 + f] * gw[(8 + f) * 16 + d];
        ws_h[(size_t)r * 32 + lane] = hv;   // [0..15]=h0, [16..31]=h1
        const float* as = head ? g1s : g0s;
        const float* ad = head ? g1d : g0d;
        float ps = hv * as[d];
        float pd = hv * ad[d];
#pragma unroll
        for (int m = 8; m >= 1; m >>= 1) {
            ps += __shfl_xor(ps, m);
            pd += __shfl_xor(pd, m);
        }
        if (d == 0) {
            // layout per row: (esrc_h0, edst_h0, esrc_h1, edst_h1)
            ws_e[(size_t)r * 4 + head * 2 + 0] = ps;
            ws_e[(size_t)r * 4 + head * 2 + 1] = pd;
        }
    }
}

// ---------------------------------------------------------------------------
// Kernel C: normalize (cooperative, into LDS) + per-row top-20 selection
// adjacency[i] = {i} ∪ { j in top20(sim row, diag=-inf) : sim>0 }
// Numerics identical to normalize-then-dot (reference order).
// ---------------------------------------------------------------------------
__global__ __launch_bounds__(256) void kC(const float* __restrict__ se,
                                          int* __restrict__ adj)
{
    __shared__ float en[N_][9];               // pad to 9 floats: bank-conflict-free
    for (int rr = threadIdx.x; rr < N_; rr += 256) {
        float v[8]; float ss = 0.f;
#pragma unroll
        for (int e = 0; e < 8; ++e) { v[e] = se[rr * 8 + e]; ss += v[e] * v[e]; }
        const float inv = 1.0f / fmaxf(sqrtf(ss), 1e-12f);
#pragma unroll
        for (int e = 0; e < 8; ++e) en[rr][e] = v[e] * inv;
    }
    __syncthreads();

    const int wave = threadIdx.x >> 6;
    const int lane = threadIdx.x & 63;
    const int i = (blockIdx.x << 2) + wave;
    float ei[8];
#pragma unroll
    for (int e = 0; e < 8; ++e) ei[e] = en[i][e];
    float v[8];
#pragma unroll
    for (int q = 0; q < 8; ++q) {
        const int j = (q << 6) + lane;
        float d = 0.f;
#pragma unroll
        for (int e = 0; e < 8; ++e) d += ei[e] * en[j][e];
        v[q] = (j == i) ? -3.4e38f : d * 0.35355339059327373f;  // 1/sqrt(8)
    }
    int cnt = 1;
    if (lane == 0) adj[i * 24 + 1] = i;          // self first
    for (int it = 0; it < 20; ++it) {
        float bv = v[0]; int bq = 0;
#pragma unroll
        for (int q = 1; q < 8; ++q) if (v[q] > bv) { bv = v[q]; bq = q; }
        int bj = (bq << 6) + lane;
#pragma unroll
        for (int m = 32; m >= 1; m >>= 1) {
            const float ov = __shfl_xor(bv, m);
            const int   oj = __shfl_xor(bj, m);
            if (ov > bv || (ov == bv && oj < bj)) { bv = ov; bj = oj; }
        }
        if (bv <= 0.f) break;                     // relu would mask the rest
        if (lane == 0) adj[i * 24 + 1 + cnt] = bj;
        cnt++;
        const int wq = bj >> 6, wl = bj & 63;
#pragma unroll
        for (int q = 0; q < 8; ++q) if (q == wq && lane == wl) v[q] = -3.4e38f;
    }
    if (lane == 0) adj[i * 24] = cnt;
}

// ---------------------------------------------------------------------------
// Kernel D: sparse GAT aggregation (lane-parallel softmax) + proj(ELU) + head
// half-wave (32 lanes) per (b,i) row; 8 rows per 256-thread block.
// Block 0 / wave 0 additionally reduces rho partials -> KL scalar.
// ---------------------------------------------------------------------------
__global__ __launch_bounds__(256) void kD(
    const float* __restrict__ ws_h, const float* __restrict__ ws_e,
    const int* __restrict__ adj,
    const float* __restrict__ proj_w, const float* __restrict__ proj_b,
    const float* __restrict__ head_w, const float* __restrict__ head_b,
    float* __restrict__ out_pred,
    const float* __restrict__ ws_rho, float* __restrict__ out_kl)
{
    const int lane = threadIdx.x & 63;
    const int wave = threadIdx.x >> 6;
    const int half = lane >> 5;
    const int t32 = lane & 31;                // phase1: neighbor slot; phase2: channel d
    const int ri = (wave << 1) + half;
    const int r = (blockIdx.x << 3) + ri;     // (b,i) row
    const int b = r >> 9;
    const int i = r & (N_ - 1);
    const int cnt = adj[i * 24];

    // own-row attention terms (esrc_h0, edst_h0, esrc_h1, edst_h1)
    const float4 er = reinterpret_cast<const float4*>(ws_e)[r];

    // ---- phase 1: lane t owns neighbor t (cnt <= 21)
    const int j = (t32 < cnt) ? adj[i * 24 + 1 + t32] : i;
    const int rj = (b << 9) | j;
    const float4 ejv = reinterpret_cast<const float4*>(ws_e)[rj];
    float e0 = er.x + ejv.y;  e0 = (e0 >= 0.f) ? e0 : 0.2f * e0;
    float e1 = er.z + ejv.w;  e1 = (e1 >= 0.f) ? e1 : 0.2f * e1;
    if (t32 >= cnt) { e0 = -3.4e38f; e1 = -3.4e38f; }
    float m0 = e0, m1 = e1;
#pragma unroll
    for (int m = 16; m >= 1; m >>= 1) {
        m0 = fmaxf(m0, __shfl_xor(m0, m));
        m1 = fmaxf(m1, __shfl_xor(m1, m));
    }
    float w0 = (t32 < cnt) ? expf(e0 - m0) : 0.f;
    float w1 = (t32 < cnt) ? expf(e1 - m1) : 0.f;
    float s0 = w0, s1 = w1;
#pragma unroll
    for (int m = 16; m >= 1; m >>= 1) {
        s0 += __shfl_xor(s0, m);
        s1 += __shfl_xor(s1, m);
    }

    // ---- phase 2: channel d = t32; gather h with independent (unrolled) loads.
    // NOTE: both weight shuffles execute CONVERGENTLY on all lanes, then a
    // per-lane select — shuffling inside a head-divergent branch is UB
    // (ds_bpermute from an exec-masked-off lane).
    const int d = t32;
    const int head = d >> 4;
    const float sinv = 1.0f / (head ? s1 : s0);
    float acc = 0.f;
#pragma unroll
    for (int t = 0; t < 21; ++t) {
        const float wt0 = __shfl(w0, t, 32);
        const float wt1 = __shfl(w1, t, 32);
        const int   jt  = __shfl(j, t, 32);
        const float wt  = head ? wt1 : wt0;
        acc += wt * ws_h[(size_t)((b << 9) | jt) * 32 + d];
    }
    const float hval = acc * sinv;   // fused GAT output channel d of row r

    // ---- proj + ELU + head (all-to-all via shuffles within the 32-half)
    float f = proj_b[d];
#pragma unroll
    for (int dd = 0; dd < 32; ++dd) {
        const float hv = __shfl(hval, dd, 32);
        f += hv * proj_w[dd * 32 + d];
    }
    f = (f > 0.f) ? f : expm1f(f);
    float p = f * head_w[d];
#pragma unroll
    for (int mm = 16; mm >= 1; mm >>= 1) p += __shfl_xor(p, mm);
    if (d == 0) out_pred[r] = p + head_b[0];

    // ---- KL tail: block 0, wave 0 only (full wave active -> shuffles safe)
    if (blockIdx.x == 0 && threadIdx.x < 64) {
        float t[8] = {0, 0, 0, 0, 0, 0, 0, 0};
        for (int q = (int)threadIdx.x; q < NBLK_A; q += 64) {
            const float4 a = reinterpret_cast<const float4*>(ws_rho)[q * 2];
            const float4 bb = reinterpret_cast<const float4*>(ws_rho)[q * 2 + 1];
            t[0] += a.x;  t[1] += a.y;  t[2] += a.z;  t[3] += a.w;
            t[4] += bb.x; t[5] += bb.y; t[6] += bb.z; t[7] += bb.w;
        }
#pragma unroll
        for (int zi = 0; zi < 8; ++zi) t[zi] = wave_reduce_sum64(t[zi]);
        if (threadIdx.x == 0) {
            float kl = 0.f;
#pragma unroll
            for (int zi = 0; zi < 8; ++zi) {
                float rh = t[zi] * (1.0f / (float)BN_);
                rh = fminf(fmaxf(rh, 1e-6f), 1.0f - 1e-6f);
                kl += 0.05f * logf(0.05f / rh) + 0.95f * logf(0.95f / (1.0f - rh));
            }
            out_kl[0] = kl;
        }
    }
}

// ---------------------------------------------------------------------------
extern "C" void kernel_launch(void* const* d_in, const int* in_sizes, int n_in,
                              void* d_out, int out_size, void* d_ws, size_t ws_size,
                              hipStream_t stream)
{
    (void)in_sizes; (void)n_in; (void)out_size; (void)ws_size;
    const float* x     = (const float*)d_in[0];
    const float* w2    = (const float*)d_in[1];
    const float* b2    = (const float*)d_in[2];
    const float* w3    = (const float*)d_in[3];
    const float* b3    = (const float*)d_in[4];
    const float* w5    = (const float*)d_in[5];
    const float* b5    = (const float*)d_in[6];
    const float* w7    = (const float*)d_in[7];
    const float* b7    = (const float*)d_in[8];
    const float* enc_w = (const float*)d_in[9];
    const float* enc_b = (const float*)d_in[10];
    const float* dec_w = (const float*)d_in[11];
    const float* dec_b = (const float*)d_in[12];
    const float* se    = (const float*)d_in[13];
    const float* g0w   = (const float*)d_in[14];
    const float* g0s   = (const float*)d_in[15];
    const float* g0d   = (const float*)d_in[16];
    const float* g1w   = (const float*)d_in[17];
    const float* g1s   = (const float*)d_in[18];
    const float* g1d   = (const float*)d_in[19];
    const float* pw    = (const float*)d_in[20];
    const float* pb    = (const float*)d_in[21];
    const float* hw    = (const float*)d_in[22];
    const float* hb    = (const float*)d_in[23];

    float* out       = (float*)d_out;
    float* out_pred  = out;                          // 16384
    float* out_recon = out + 16384;                  // 4194304
    float* out_kl    = out + 16384 + 4194304;        // 1
    float* out_sdev  = out_kl + 1;                   // 16384

    float* ws_h   = (float*)d_ws;                    // BN_*32
    float* ws_e   = ws_h + (size_t)BN_ * 32;         // BN_*4
    float* ws_rho = ws_e + (size_t)BN_ * 4;          // NBLK_A*8
    int*   ws_adj = (int*)(ws_rho + (size_t)NBLK_A * 8);  // N_*24 ints

    hipLaunchKernelGGL(kA, dim3(NBLK_A), dim3(256), 0, stream,
                       x, w2, b2, w3, b3, w5, b5, w7, b7,
                       enc_w, enc_b, dec_w, dec_b, se,
                       g0w, g0s, g0d, g1w, g1s, g1d,
                       out_recon, out_sdev, ws_h, ws_e, ws_rho);
    hipLaunchKernelGGL(kC, dim3(N_ / 4), dim3(256), 0, stream, se, ws_adj);
    hipLaunchKernelGGL(kD, dim3(BN_ / 8), dim3(256), 0, stream,
                       ws_h, ws_e, ws_adj, pw, pb, hw, hb, out_pred,
                       ws_rho, out_kl);
}

// Round 4
// 62.991 us; speedup vs baseline: 1.3934x; 1.0594x over previous
//
#include <hip/hip_runtime.h>
#include <math.h>

#define B_   32
#define N_   512
#define W_   256
#define BN_  (B_*N_)        // 16384
#define NBLK_A 4096         // BN_/4 rows-per-block
#define NBLK_C 128          // adjacency blocks (4 rows each)

__device__ __forceinline__ float wave_reduce_sum64(float v) {
#pragma unroll
    for (int m = 32; m >= 1; m >>= 1) v += __shfl_xor(v, m);
    return v;
}

// ---------------------------------------------------------------------------
// Kernel AC: blocks [0,4096) = per-row MSTCN->z->recon + stats + GAT h/e
//            blocks [4096,4224) = graph-learning top-20 adjacency
// ---------------------------------------------------------------------------
__global__ __launch_bounds__(256) void kAC(
    const float* __restrict__ x,
    const float* __restrict__ w2, const float* __restrict__ b2,
    const float* __restrict__ w3, const float* __restrict__ b3,
    const float* __restrict__ w5, const float* __restrict__ b5,
    const float* __restrict__ w7, const float* __restrict__ b7,
    const float* __restrict__ enc_w, const float* __restrict__ enc_b,
    const float* __restrict__ dec_w, const float* __restrict__ dec_b,
    const float* __restrict__ se,
    const float* __restrict__ g0w, const float* __restrict__ g0s, const float* __restrict__ g0d,
    const float* __restrict__ g1w, const float* __restrict__ g1s, const float* __restrict__ g1d,
    float* __restrict__ out_recon, float* __restrict__ out_sdev,
    float* __restrict__ ws_h, float* __restrict__ ws_e, float* __restrict__ ws_rho,
    int* __restrict__ adj)
{
    __shared__ float en[N_][9];               // kC branch (18.4 KB; 8 blk/CU ok)
    __shared__ float lds_rho[4][8];
    const int wave = threadIdx.x >> 6;
    const int lane = threadIdx.x & 63;

    if (blockIdx.x >= NBLK_A) {
        // ================= kC: normalize + top-20 per row =================
        for (int rr = threadIdx.x; rr < N_; rr += 256) {
            float v[8]; float ss = 0.f;
#pragma unroll
            for (int e = 0; e < 8; ++e) { v[e] = se[rr * 8 + e]; ss += v[e] * v[e]; }
            const float inv = 1.0f / fmaxf(sqrtf(ss), 1e-12f);
#pragma unroll
            for (int e = 0; e < 8; ++e) en[rr][e] = v[e] * inv;
        }
        __syncthreads();

        const int i = ((blockIdx.x - NBLK_A) << 2) + wave;
        float ei[8];
#pragma unroll
        for (int e = 0; e < 8; ++e) ei[e] = en[i][e];
        float v[8];
#pragma unroll
        for (int q = 0; q < 8; ++q) {
            const int j = (q << 6) + lane;
            float d = 0.f;
#pragma unroll
            for (int e = 0; e < 8; ++e) d += ei[e] * en[j][e];
            v[q] = (j == i) ? -3.4e38f : d * 0.35355339059327373f;  // 1/sqrt(8)
        }
        int cnt = 1;
        if (lane == 0) adj[i * 24 + 1] = i;          // self first
        for (int it = 0; it < 20; ++it) {
            float bv = v[0]; int bq = 0;
#pragma unroll
            for (int q = 1; q < 8; ++q) if (v[q] > bv) { bv = v[q]; bq = q; }
            int bj = (bq << 6) + lane;
#pragma unroll
            for (int m = 32; m >= 1; m >>= 1) {
                const float ov = __shfl_xor(bv, m);
                const int   oj = __shfl_xor(bj, m);
                if (ov > bv || (ov == bv && oj < bj)) { bv = ov; bj = oj; }
            }
            if (bv <= 0.f) break;                     // relu masks the rest
            if (lane == 0) adj[i * 24 + 1 + cnt] = bj;
            cnt++;
            const int wq = bj >> 6, wl = bj & 63;
#pragma unroll
            for (int q = 0; q < 8; ++q) if (q == wq && lane == wl) v[q] = -3.4e38f;
        }
        if (lane == 0) adj[i * 24] = cnt;
        return;
    }

    // ===================== kA: one wave per (b,n) row =====================
    const int r = (blockIdx.x << 2) + wave;      // row id in [0, BN_)
    const int n = r & (N_ - 1);

    // ---- load row of x: 64 lanes x float4 = 256 floats
    const float4 xv = reinterpret_cast<const float4*>(x)[r * 64 + lane];
    const float S = wave_reduce_sum64(xv.x + xv.y + xv.z + xv.w);
    const float P1 = __shfl(xv.x, 0);
    const float P2 = P1 + __shfl(xv.y, 0);
    const float P3 = P2 + __shfl(xv.z, 0);
    const float Q1 = __shfl(xv.w, 63);
    const float Q2 = Q1 + __shfl(xv.z, 63);
    const float Q3 = Q2 + __shfl(xv.y, 63);

    // ---- node_feat: one channel per lane. feats order: k=2,3,5,7 x 16ch
    const int ki = lane >> 4, c = lane & 15;
    const int k  = (ki == 0) ? 2 : (ki == 1) ? 3 : (ki == 2) ? 5 : 7;
    const int pl = (k - 1) >> 1;
    const float* cw = (ki == 0) ? w2 : (ki == 1) ? w3 : (ki == 2) ? w5 : w7;
    const float* cb = (ki == 0) ? b2 : (ki == 1) ? b3 : (ki == 2) ? b5 : b7;
    float acc = 0.f;
    for (int j = 0; j < k; ++j) {
        const int o = j - pl;
        const float corr = (o == 0) ? 0.f :
                           (o == 1) ? P1 : (o == 2) ? P2 : (o == 3) ? P3 :
                           (o == -1) ? Q1 : (o == -2) ? Q2 : Q3;
        acc += cw[c * k + j] * (S - corr);
    }
    const float nf = cb[c] + acc * (1.0f / (float)W_);

    // ---- z[8] = node_feat @ enc_w + enc_b   (reduce across 64 lanes)
    float z[8];
    {
        const float4 e0 = reinterpret_cast<const float4*>(enc_w)[lane * 2];
        const float4 e1 = reinterpret_cast<const float4*>(enc_w)[lane * 2 + 1];
        z[0] = nf * e0.x; z[1] = nf * e0.y; z[2] = nf * e0.z; z[3] = nf * e0.w;
        z[4] = nf * e1.x; z[5] = nf * e1.y; z[6] = nf * e1.z; z[7] = nf * e1.w;
#pragma unroll
        for (int zi = 0; zi < 8; ++zi) z[zi] = wave_reduce_sum64(z[zi]) + enc_b[zi];
    }

    // ---- recon row = z @ dec_w + dec_b  (4 outputs per lane, float4 store)
    {
        float4 rec = reinterpret_cast<const float4*>(dec_b)[lane];
#pragma unroll
        for (int zi = 0; zi < 8; ++zi) {
            const float4 dw = reinterpret_cast<const float4*>(dec_w)[zi * 64 + lane];
            rec.x += z[zi] * dw.x; rec.y += z[zi] * dw.y;
            rec.z += z[zi] * dw.z; rec.w += z[zi] * dw.w;
        }
        reinterpret_cast<float4*>(out_recon)[r * 64 + lane] = rec;
    }

    // ---- act stats: lane l computes sigmoid(z[l&7]) — 1 expf/thread.
    // 8-lane-group butterfly gives each group's sum of |act - rho|.
    {
        const float zl = z[lane & 7];
        const float a = 1.0f / (1.0f + __expf(-zl));
        float sd = fabsf(a - 0.05f);
#pragma unroll
        for (int m = 4; m >= 1; m >>= 1) sd += __shfl_xor(sd, m);
        if (lane < 8) lds_rho[wave][lane] = a;
        if (lane == 0) out_sdev[r] = sd * 0.125f;
    }
    __syncthreads();
    if (threadIdx.x < 8) {
        const float t = lds_rho[0][threadIdx.x] + lds_rho[1][threadIdx.x]
                      + lds_rho[2][threadIdx.x] + lds_rho[3][threadIdx.x];
        ws_rho[(blockIdx.x << 3) + threadIdx.x] = t;
    }

    // ---- GAT precompute: h0/h1 (16 each), e_src/e_dst per head
    if (lane < 32) {
        const int d = lane & 15;
        const int head = lane >> 4;
        const float* gw = head ? g1w : g0w;
        float hv = 0.f;
#pragma unroll
        for (int f = 0; f < 8; ++f) hv += z[f] * gw[f * 16 + d];
#pragma unroll
        for (int f = 0; f < 8; ++f) hv += se[n * 8 + f] * gw[(8 + f) * 16 + d];
        ws_h[(size_t)r * 32 + lane] = hv;   // [0..15]=h0, [16..31]=h1
        const float* as = head ? g1s : g0s;
        const float* ad = head ? g1d : g0d;
        float ps = hv * as[d];
        float pd = hv * ad[d];
#pragma unroll
        for (int m = 8; m >= 1; m >>= 1) {
            ps += __shfl_xor(ps, m);
            pd += __shfl_xor(pd, m);
        }
        if (d == 0) {
            // layout per row: (esrc_h0, edst_h0, esrc_h1, edst_h1)
            ws_e[(size_t)r * 4 + head * 2 + 0] = ps;
            ws_e[(size_t)r * 4 + head * 2 + 1] = pd;
        }
    }
}

// ---------------------------------------------------------------------------
// Kernel D: sparse GAT aggregation (lane-parallel softmax) + proj(ELU) + head
// half-wave (32 lanes) per (b,i) row; 8 rows per 256-thread block.
// Block 0 / wave 0 additionally reduces rho partials -> KL scalar.
// ---------------------------------------------------------------------------
__global__ __launch_bounds__(256) void kD(
    const float* __restrict__ ws_h, const float* __restrict__ ws_e,
    const int* __restrict__ adj,
    const float* __restrict__ proj_w, const float* __restrict__ proj_b,
    const float* __restrict__ head_w, const float* __restrict__ head_b,
    float* __restrict__ out_pred,
    const float* __restrict__ ws_rho, float* __restrict__ out_kl)
{
    const int lane = threadIdx.x & 63;
    const int wave = threadIdx.x >> 6;
    const int half = lane >> 5;
    const int t32 = lane & 31;                // phase1: neighbor slot; phase2: channel d
    const int ri = (wave << 1) + half;
    const int r = (blockIdx.x << 3) + ri;     // (b,i) row
    const int b = r >> 9;
    const int i = r & (N_ - 1);
    const int cnt = adj[i * 24];

    // own-row attention terms (esrc_h0, edst_h0, esrc_h1, edst_h1)
    const float4 er = reinterpret_cast<const float4*>(ws_e)[r];

    // ---- phase 1: lane t owns neighbor t (cnt <= 21)
    const int j = (t32 < cnt) ? adj[i * 24 + 1 + t32] : i;
    const int rj = (b << 9) | j;
    const float4 ejv = reinterpret_cast<const float4*>(ws_e)[rj];
    float e0 = er.x + ejv.y;  e0 = (e0 >= 0.f) ? e0 : 0.2f * e0;
    float e1 = er.z + ejv.w;  e1 = (e1 >= 0.f) ? e1 : 0.2f * e1;
    if (t32 >= cnt) { e0 = -3.4e38f; e1 = -3.4e38f; }
    float m0 = e0, m1 = e1;
#pragma unroll
    for (int m = 16; m >= 1; m >>= 1) {
        m0 = fmaxf(m0, __shfl_xor(m0, m));
        m1 = fmaxf(m1, __shfl_xor(m1, m));
    }
    float w0 = (t32 < cnt) ? __expf(e0 - m0) : 0.f;
    float w1 = (t32 < cnt) ? __expf(e1 - m1) : 0.f;
    float s0 = w0, s1 = w1;
#pragma unroll
    for (int m = 16; m >= 1; m >>= 1) {
        s0 += __shfl_xor(s0, m);
        s1 += __shfl_xor(s1, m);
    }

    // ---- phase 2: channel d = t32; gather h with independent (unrolled) loads.
    // Both weight shuffles execute CONVERGENTLY, then per-lane select (head-
    // divergent shuffle is UB: ds_bpermute from exec-masked-off lane).
    const int d = t32;
    const int head = d >> 4;
    const float sinv = 1.0f / (head ? s1 : s0);
    float acc = 0.f;
#pragma unroll
    for (int t = 0; t < 21; ++t) {
        const float wt0 = __shfl(w0, t, 32);
        const float wt1 = __shfl(w1, t, 32);
        const int   jt  = __shfl(j, t, 32);
        const float wt  = head ? wt1 : wt0;
        acc += wt * ws_h[(size_t)((b << 9) | jt) * 32 + d];
    }
    const float hval = acc * sinv;   // fused GAT output channel d of row r

    // ---- proj + ELU + head (all-to-all via shuffles within the 32-half)
    float f = proj_b[d];
#pragma unroll
    for (int dd = 0; dd < 32; ++dd) {
        const float hv = __shfl(hval, dd, 32);
        f += hv * proj_w[dd * 32 + d];
    }
    f = (f > 0.f) ? f : expm1f(f);
    float p = f * head_w[d];
#pragma unroll
    for (int mm = 16; mm >= 1; mm >>= 1) p += __shfl_xor(p, mm);
    if (d == 0) out_pred[r] = p + head_b[0];

    // ---- KL tail: block 0, wave 0 only (full wave active -> shuffles safe)
    if (blockIdx.x == 0 && threadIdx.x < 64) {
        float t[8] = {0, 0, 0, 0, 0, 0, 0, 0};
        for (int q = (int)threadIdx.x; q < NBLK_A; q += 64) {
            const float4 a = reinterpret_cast<const float4*>(ws_rho)[q * 2];
            const float4 bb = reinterpret_cast<const float4*>(ws_rho)[q * 2 + 1];
            t[0] += a.x;  t[1] += a.y;  t[2] += a.z;  t[3] += a.w;
            t[4] += bb.x; t[5] += bb.y; t[6] += bb.z; t[7] += bb.w;
        }
#pragma unroll
        for (int zi = 0; zi < 8; ++zi) t[zi] = wave_reduce_sum64(t[zi]);
        if (threadIdx.x == 0) {
            float kl = 0.f;
#pragma unroll
            for (int zi = 0; zi < 8; ++zi) {
                float rh = t[zi] * (1.0f / (float)BN_);
                rh = fminf(fmaxf(rh, 1e-6f), 1.0f - 1e-6f);
                kl += 0.05f * logf(0.05f / rh) + 0.95f * logf(0.95f / (1.0f - rh));
            }
            out_kl[0] = kl;
        }
    }
}

// ---------------------------------------------------------------------------
extern "C" void kernel_launch(void* const* d_in, const int* in_sizes, int n_in,
                              void* d_out, int out_size, void* d_ws, size_t ws_size,
                              hipStream_t stream)
{
    (void)in_sizes; (void)n_in; (void)out_size; (void)ws_size;
    const float* x     = (const float*)d_in[0];
    const float* w2    = (const float*)d_in[1];
    const float* b2    = (const float*)d_in[2];
    const float* w3    = (const float*)d_in[3];
    const float* b3    = (const float*)d_in[4];
    const float* w5    = (const float*)d_in[5];
    const float* b5    = (const float*)d_in[6];
    const float* w7    = (const float*)d_in[7];
    const float* b7    = (const float*)d_in[8];
    const float* enc_w = (const float*)d_in[9];
    const float* enc_b = (const float*)d_in[10];
    const float* dec_w = (const float*)d_in[11];
    const float* dec_b = (const float*)d_in[12];
    const float* se    = (const float*)d_in[13];
    const float* g0w   = (const float*)d_in[14];
    const float* g0s   = (const float*)d_in[15];
    const float* g0d   = (const float*)d_in[16];
    const float* g1w   = (const float*)d_in[17];
    const float* g1s   = (const float*)d_in[18];
    const float* g1d   = (const float*)d_in[19];
    const float* pw    = (const float*)d_in[20];
    const float* pb    = (const float*)d_in[21];
    const float* hw    = (const float*)d_in[22];
    const float* hb    = (const float*)d_in[23];

    float* out       = (float*)d_out;
    float* out_pred  = out;                          // 16384
    float* out_recon = out + 16384;                  // 4194304
    float* out_kl    = out + 16384 + 4194304;        // 1
    float* out_sdev  = out_kl + 1;                   // 16384

    float* ws_h   = (float*)d_ws;                    // BN_*32
    float* ws_e   = ws_h + (size_t)BN_ * 32;         // BN_*4
    float* ws_rho = ws_e + (size_t)BN_ * 4;          // NBLK_A*8
    int*   ws_adj = (int*)(ws_rho + (size_t)NBLK_A * 8);  // N_*24 ints

    hipLaunchKernelGGL(kAC, dim3(NBLK_A + NBLK_C), dim3(256), 0, stream,
                       x, w2, b2, w3, b3, w5, b5, w7, b7,
                       enc_w, enc_b, dec_w, dec_b, se,
                       g0w, g0s, g0d, g1w, g1s, g1d,
                       out_recon, out_sdev, ws_h, ws_e, ws_rho, ws_adj);
    hipLaunchKernelGGL(kD, dim3(BN_ / 8), dim3(256), 0, stream,
                       ws_h, ws_e, ws_adj, pw, pb, hw, hb, out_pred,
                       ws_rho, out_kl);
}

// Round 5
// 58.655 us; speedup vs baseline: 1.4964x; 1.0739x over previous
//
#include <hip/hip_runtime.h>
#include <math.h>

#define B_   32
#define N_   512
#define W_   256
#define BN_  (B_*N_)        // 16384
#define NBLK_A 1024         // kA blocks: 16 rows each (4 waves x 4 rows)
#define NBLK_C 128          // adjacency blocks (4 rows each)
#define RHOG   4096         // rho partial groups (one per kA wave)

__device__ __forceinline__ float wave_reduce_sum64(float v) {
#pragma unroll
    for (int m = 32; m >= 1; m >>= 1) v += __shfl_xor(v, m);
    return v;
}

// static select of z[rr][zi] (runtime rr/zi would send the array to scratch)
__device__ __forceinline__ float sel32(const float z[4][8], int rr, int zi) {
    float v = 0.f;
#pragma unroll
    for (int q = 0; q < 4; ++q)
#pragma unroll
        for (int p = 0; p < 8; ++p)
            v = (rr == q && zi == p) ? z[q][p] : v;
    return v;
}

// ---------------------------------------------------------------------------
// Kernel AC: blocks [0,1024): per-row MSTCN->z->recon + stats + GAT h/e,
//            4 rows per WAVE (16 per block) for ILP — no __syncthreads.
//            blocks [1024,1152): graph-learning top-20 adjacency.
// ---------------------------------------------------------------------------
__global__ __launch_bounds__(256) void kAC(
    const float* __restrict__ x,
    const float* __restrict__ w2, const float* __restrict__ b2,
    const float* __restrict__ w3, const float* __restrict__ b3,
    const float* __restrict__ w5, const float* __restrict__ b5,
    const float* __restrict__ w7, const float* __restrict__ b7,
    const float* __restrict__ enc_w, const float* __restrict__ enc_b,
    const float* __restrict__ dec_w, const float* __restrict__ dec_b,
    const float* __restrict__ se,
    const float* __restrict__ g0w, const float* __restrict__ g0s, const float* __restrict__ g0d,
    const float* __restrict__ g1w, const float* __restrict__ g1s, const float* __restrict__ g1d,
    float* __restrict__ out_recon, float* __restrict__ out_sdev,
    float* __restrict__ ws_h, float* __restrict__ ws_e, float* __restrict__ ws_rho,
    int* __restrict__ adj)
{
    __shared__ float en[N_][9];               // used only by kC blocks
    const int wave = threadIdx.x >> 6;
    const int lane = threadIdx.x & 63;

    if (blockIdx.x >= NBLK_A) {
        // ================= kC: normalize + top-20 per row =================
        for (int rr = threadIdx.x; rr < N_; rr += 256) {
            float v[8]; float ss = 0.f;
#pragma unroll
            for (int e = 0; e < 8; ++e) { v[e] = se[rr * 8 + e]; ss += v[e] * v[e]; }
            const float inv = 1.0f / fmaxf(sqrtf(ss), 1e-12f);
#pragma unroll
            for (int e = 0; e < 8; ++e) en[rr][e] = v[e] * inv;
        }
        __syncthreads();

        const int i = ((blockIdx.x - NBLK_A) << 2) + wave;
        float ei[8];
#pragma unroll
        for (int e = 0; e < 8; ++e) ei[e] = en[i][e];
        float v[8];
#pragma unroll
        for (int q = 0; q < 8; ++q) {
            const int j = (q << 6) + lane;
            float d = 0.f;
#pragma unroll
            for (int e = 0; e < 8; ++e) d += ei[e] * en[j][e];
            v[q] = (j == i) ? -3.4e38f : d * 0.35355339059327373f;  // 1/sqrt(8)
        }
        int cnt = 1;
        if (lane == 0) adj[i * 24 + 1] = i;          // self first
        for (int it = 0; it < 20; ++it) {
            float bv = v[0]; int bq = 0;
#pragma unroll
            for (int q = 1; q < 8; ++q) if (v[q] > bv) { bv = v[q]; bq = q; }
            int bj = (bq << 6) + lane;
#pragma unroll
            for (int m = 32; m >= 1; m >>= 1) {
                const float ov = __shfl_xor(bv, m);
                const int   oj = __shfl_xor(bj, m);
                if (ov > bv || (ov == bv && oj < bj)) { bv = ov; bj = oj; }
            }
            if (bv <= 0.f) break;                     // relu masks the rest
            if (lane == 0) adj[i * 24 + 1 + cnt] = bj;
            cnt++;
            const int wq = bj >> 6, wl = bj & 63;
#pragma unroll
            for (int q = 0; q < 8; ++q) if (q == wq && lane == wl) v[q] = -3.4e38f;
        }
        if (lane == 0) adj[i * 24] = cnt;
        return;
    }

    // ================ kA: 4 rows per wave, fully independent ================
    const int r0 = (blockIdx.x << 4) + (wave << 2);   // first of this wave's 4 rows

    // ---- 4 x-row loads issued together (4 outstanding HBM requests)
    float4 xv[4];
#pragma unroll
    for (int rr = 0; rr < 4; ++rr)
        xv[rr] = reinterpret_cast<const float4*>(x)[(size_t)(r0 + rr) * 64 + lane];

    float S[4], P1[4], P2[4], P3[4], Q1[4], Q2[4], Q3[4];
#pragma unroll
    for (int rr = 0; rr < 4; ++rr) {
        S[rr]  = wave_reduce_sum64(xv[rr].x + xv[rr].y + xv[rr].z + xv[rr].w);
        P1[rr] = __shfl(xv[rr].x, 0);
        P2[rr] = P1[rr] + __shfl(xv[rr].y, 0);
        P3[rr] = P2[rr] + __shfl(xv[rr].z, 0);
        Q1[rr] = __shfl(xv[rr].w, 63);
        Q2[rr] = Q1[rr] + __shfl(xv[rr].z, 63);
        Q3[rr] = Q2[rr] + __shfl(xv[rr].y, 63);
    }

    // ---- node_feat: one channel per lane; weights hoisted once per wave
    const int ki = lane >> 4, c = lane & 15;
    const int k  = (ki == 0) ? 2 : (ki == 1) ? 3 : (ki == 2) ? 5 : 7;
    const int pl = (k - 1) >> 1;
    const float* cw = (ki == 0) ? w2 : (ki == 1) ? w3 : (ki == 2) ? w5 : w7;
    const float* cb = (ki == 0) ? b2 : (ki == 1) ? b3 : (ki == 2) ? b5 : b7;
    float cwv[7];
#pragma unroll
    for (int j = 0; j < 7; ++j) cwv[j] = (j < k) ? cw[c * k + j] : 0.f;
    const float cbc = cb[c];
    float nf[4];
#pragma unroll
    for (int rr = 0; rr < 4; ++rr) {
        float acc = 0.f;
#pragma unroll
        for (int j = 0; j < 7; ++j) {
            const int o = j - pl;
            const float corr = (o == 0) ? 0.f :
                               (o == 1) ? P1[rr] : (o == 2) ? P2[rr] : (o == 3) ? P3[rr] :
                               (o == -1) ? Q1[rr] : (o == -2) ? Q2[rr] : (o == -3) ? Q3[rr] : 0.f;
            acc += cwv[j] * (S[rr] - corr);   // cwv[j]==0 for j>=k
        }
        nf[rr] = cbc + acc * (1.0f / (float)W_);
    }

    // ---- z[4][8]: 32 independent reduction chains, weights loaded once
    const float4 e0 = reinterpret_cast<const float4*>(enc_w)[lane * 2];
    const float4 e1 = reinterpret_cast<const float4*>(enc_w)[lane * 2 + 1];
    float z[4][8];
#pragma unroll
    for (int rr = 0; rr < 4; ++rr) {
        z[rr][0] = nf[rr] * e0.x; z[rr][1] = nf[rr] * e0.y;
        z[rr][2] = nf[rr] * e0.z; z[rr][3] = nf[rr] * e0.w;
        z[rr][4] = nf[rr] * e1.x; z[rr][5] = nf[rr] * e1.y;
        z[rr][6] = nf[rr] * e1.z; z[rr][7] = nf[rr] * e1.w;
    }
#pragma unroll
    for (int m = 32; m >= 1; m >>= 1)
#pragma unroll
        for (int rr = 0; rr < 4; ++rr)
#pragma unroll
            for (int zi = 0; zi < 8; ++zi)
                z[rr][zi] += __shfl_xor(z[rr][zi], m);
#pragma unroll
    for (int zi = 0; zi < 8; ++zi) {
        const float eb = enc_b[zi];
#pragma unroll
        for (int rr = 0; rr < 4; ++rr) z[rr][zi] += eb;
    }

    // ---- recon: dec_w loaded once per wave, applied to 4 rows
    {
        const float4 db = reinterpret_cast<const float4*>(dec_b)[lane];
        float4 rec[4];
#pragma unroll
        for (int rr = 0; rr < 4; ++rr) rec[rr] = db;
#pragma unroll
        for (int zi = 0; zi < 8; ++zi) {
            const float4 dw = reinterpret_cast<const float4*>(dec_w)[zi * 64 + lane];
#pragma unroll
            for (int rr = 0; rr < 4; ++rr) {
                rec[rr].x += z[rr][zi] * dw.x; rec[rr].y += z[rr][zi] * dw.y;
                rec[rr].z += z[rr][zi] * dw.z; rec[rr].w += z[rr][zi] * dw.w;
            }
        }
#pragma unroll
        for (int rr = 0; rr < 4; ++rr)
            reinterpret_cast<float4*>(out_recon)[(size_t)(r0 + rr) * 64 + lane] = rec[rr];
    }

    // ---- act stats: lane (rr,zi)=(lane>>3&3, lane&7); static select of z
    {
        const int rr = (lane >> 3) & 3, zi = lane & 7;
        const float zl = sel32(z, rr, zi);
        const float a = 1.0f / (1.0f + __expf(-zl));
        float sd = fabsf(a - 0.05f);
        sd += __shfl_xor(sd, 1); sd += __shfl_xor(sd, 2); sd += __shfl_xor(sd, 4);
        float rho = a;
        rho += __shfl_xor(rho, 8); rho += __shfl_xor(rho, 16);
        const int gid = (blockIdx.x << 2) + wave;
        if (lane < 8) ws_rho[gid * 8 + lane] = rho;          // sum of 4 rows' act
        if (lane < 32 && zi == 0) out_sdev[r0 + rr] = sd * 0.125f;
    }

    // ---- GAT precompute: gw cached in regs once, reused across 4 rows
    if (lane < 32) {
        const int d = lane & 15, head = lane >> 4;
        const float* gw = head ? g1w : g0w;
        float gwr[16];
#pragma unroll
        for (int f = 0; f < 16; ++f) gwr[f] = gw[f * 16 + d];
        const float asd  = (head ? g1s : g0s)[d];
        const float add_ = (head ? g1d : g0d)[d];
#pragma unroll
        for (int rr = 0; rr < 4; ++rr) {
            const int rR = r0 + rr, nR = rR & (N_ - 1);
            float hv = 0.f;
#pragma unroll
            for (int f = 0; f < 8; ++f) hv += z[rr][f] * gwr[f];
#pragma unroll
            for (int f = 0; f < 8; ++f) hv += se[nR * 8 + f] * gwr[8 + f];
            ws_h[(size_t)rR * 32 + lane] = hv;
            float ps = hv * asd, pd = hv * add_;
#pragma unroll
            for (int m = 8; m >= 1; m >>= 1) {
                ps += __shfl_xor(ps, m);
                pd += __shfl_xor(pd, m);
            }
            if (d == 0) {
                ws_e[(size_t)rR * 4 + head * 2 + 0] = ps;
                ws_e[(size_t)rR * 4 + head * 2 + 1] = pd;
            }
        }
    }
}

// ---------------------------------------------------------------------------
// Kernel D: sparse GAT aggregation (lane-parallel softmax) + proj(ELU) + head
// half-wave (32 lanes) per (b,i) row; 8 rows per 256-thread block.
// Block 0 / wave 0 additionally reduces rho partials -> KL scalar.
// ---------------------------------------------------------------------------
__global__ __launch_bounds__(256) void kD(
    const float* __restrict__ ws_h, const float* __restrict__ ws_e,
    const int* __restrict__ adj,
    const float* __restrict__ proj_w, const float* __restrict__ proj_b,
    const float* __restrict__ head_w, const float* __restrict__ head_b,
    float* __restrict__ out_pred,
    const float* __restrict__ ws_rho, float* __restrict__ out_kl)
{
    const int lane = threadIdx.x & 63;
    const int wave = threadIdx.x >> 6;
    const int half = lane >> 5;
    const int t32 = lane & 31;                // phase1: neighbor slot; phase2: channel d
    const int ri = (wave << 1) + half;
    const int r = (blockIdx.x << 3) + ri;     // (b,i) row
    const int b = r >> 9;
    const int i = r & (N_ - 1);
    const int cnt = adj[i * 24];

    // own-row attention terms (esrc_h0, edst_h0, esrc_h1, edst_h1)
    const float4 er = reinterpret_cast<const float4*>(ws_e)[r];

    // ---- phase 1: lane t owns neighbor t (cnt <= 21)
    const int j = (t32 < cnt) ? adj[i * 24 + 1 + t32] : i;
    const int rj = (b << 9) | j;
    const float4 ejv = reinterpret_cast<const float4*>(ws_e)[rj];
    float e0 = er.x + ejv.y;  e0 = (e0 >= 0.f) ? e0 : 0.2f * e0;
    float e1 = er.z + ejv.w;  e1 = (e1 >= 0.f) ? e1 : 0.2f * e1;
    if (t32 >= cnt) { e0 = -3.4e38f; e1 = -3.4e38f; }
    float m0 = e0, m1 = e1;
#pragma unroll
    for (int m = 16; m >= 1; m >>= 1) {
        m0 = fmaxf(m0, __shfl_xor(m0, m));
        m1 = fmaxf(m1, __shfl_xor(m1, m));
    }
    float w0 = (t32 < cnt) ? __expf(e0 - m0) : 0.f;
    float w1 = (t32 < cnt) ? __expf(e1 - m1) : 0.f;
    float s0 = w0, s1 = w1;
#pragma unroll
    for (int m = 16; m >= 1; m >>= 1) {
        s0 += __shfl_xor(s0, m);
        s1 += __shfl_xor(s1, m);
    }

    // ---- phase 2: channel d = t32; gather h with independent (unrolled) loads.
    // Both weight shuffles execute CONVERGENTLY, then per-lane select (head-
    // divergent shuffle is UB: ds_bpermute from exec-masked-off lane).
    const int d = t32;
    const int head = d >> 4;
    const float sinv = 1.0f / (head ? s1 : s0);
    float acc = 0.f;
#pragma unroll
    for (int t = 0; t < 21; ++t) {
        const float wt0 = __shfl(w0, t, 32);
        const float wt1 = __shfl(w1, t, 32);
        const int   jt  = __shfl(j, t, 32);
        const float wt  = head ? wt1 : wt0;
        acc += wt * ws_h[(size_t)((b << 9) | jt) * 32 + d];
    }
    const float hval = acc * sinv;   // fused GAT output channel d of row r

    // ---- proj + ELU + head (all-to-all via shuffles within the 32-half)
    float f = proj_b[d];
#pragma unroll
    for (int dd = 0; dd < 32; ++dd) {
        const float hv = __shfl(hval, dd, 32);
        f += hv * proj_w[dd * 32 + d];
    }
    f = (f > 0.f) ? f : expm1f(f);
    float p = f * head_w[d];
#pragma unroll
    for (int mm = 16; mm >= 1; mm >>= 1) p += __shfl_xor(p, mm);
    if (d == 0) out_pred[r] = p + head_b[0];

    // ---- KL tail: block 0, wave 0 only (full wave active -> shuffles safe)
    if (blockIdx.x == 0 && threadIdx.x < 64) {
        float t[8] = {0, 0, 0, 0, 0, 0, 0, 0};
        for (int q = (int)threadIdx.x; q < RHOG; q += 64) {
            const float4 a = reinterpret_cast<const float4*>(ws_rho)[q * 2];
            const float4 bb = reinterpret_cast<const float4*>(ws_rho)[q * 2 + 1];
            t[0] += a.x;  t[1] += a.y;  t[2] += a.z;  t[3] += a.w;
            t[4] += bb.x; t[5] += bb.y; t[6] += bb.z; t[7] += bb.w;
        }
#pragma unroll
        for (int zi = 0; zi < 8; ++zi) t[zi] = wave_reduce_sum64(t[zi]);
        if (threadIdx.x == 0) {
            float kl = 0.f;
#pragma unroll
            for (int zi = 0; zi < 8; ++zi) {
                float rh = t[zi] * (1.0f / (float)BN_);
                rh = fminf(fmaxf(rh, 1e-6f), 1.0f - 1e-6f);
                kl += 0.05f * logf(0.05f / rh) + 0.95f * logf(0.95f / (1.0f - rh));
            }
            out_kl[0] = kl;
        }
    }
}

// ---------------------------------------------------------------------------
extern "C" void kernel_launch(void* const* d_in, const int* in_sizes, int n_in,
                              void* d_out, int out_size, void* d_ws, size_t ws_size,
                              hipStream_t stream)
{
    (void)in_sizes; (void)n_in; (void)out_size; (void)ws_size;
    const float* x     = (const float*)d_in[0];
    const float* w2    = (const float*)d_in[1];
    const float* b2    = (const float*)d_in[2];
    const float* w3    = (const float*)d_in[3];
    const float* b3    = (const float*)d_in[4];
    const float* w5    = (const float*)d_in[5];
    const float* b5    = (const float*)d_in[6];
    const float* w7    = (const float*)d_in[7];
    const float* b7    = (const float*)d_in[8];
    const float* enc_w = (const float*)d_in[9];
    const float* enc_b = (const float*)d_in[10];
    const float* dec_w = (const float*)d_in[11];
    const float* dec_b = (const float*)d_in[12];
    const float* se    = (const float*)d_in[13];
    const float* g0w   = (const float*)d_in[14];
    const float* g0s   = (const float*)d_in[15];
    const float* g0d   = (const float*)d_in[16];
    const float* g1w   = (const float*)d_in[17];
    const float* g1s   = (const float*)d_in[18];
    const float* g1d   = (const float*)d_in[19];
    const float* pw    = (const float*)d_in[20];
    const float* pb    = (const float*)d_in[21];
    const float* hw    = (const float*)d_in[22];
    const float* hb    = (const float*)d_in[23];

    float* out       = (float*)d_out;
    float* out_pred  = out;                          // 16384
    float* out_recon = out + 16384;                  // 4194304
    float* out_kl    = out + 16384 + 4194304;        // 1
    float* out_sdev  = out_kl + 1;                   // 16384

    float* ws_h   = (float*)d_ws;                    // BN_*32
    float* ws_e   = ws_h + (size_t)BN_ * 32;         // BN_*4
    float* ws_rho = ws_e + (size_t)BN_ * 4;          // RHOG*8
    int*   ws_adj = (int*)(ws_rho + (size_t)RHOG * 8);    // N_*24 ints

    hipLaunchKernelGGL(kAC, dim3(NBLK_A + NBLK_C), dim3(256), 0, stream,
                       x, w2, b2, w3, b3, w5, b5, w7, b7,
                       enc_w, enc_b, dec_w, dec_b, se,
                       g0w, g0s, g0d, g1w, g1s, g1d,
                       out_recon, out_sdev, ws_h, ws_e, ws_rho, ws_adj);
    hipLaunchKernelGGL(kD, dim3(BN_ / 8), dim3(256), 0, stream,
                       ws_h, ws_e, ws_adj, pw, pb, hw, hb, out_pred,
                       ws_rho, out_kl);
}